// Round 1
// 325.581 us; speedup vs baseline: 1.0047x; 1.0047x over previous
//
#include <hip/hip_runtime.h>
#include <hip/hip_bf16.h>

#define K_DIM 256
#define RSTRIDE 128   // padded CSR row stride; in-deg max ~58 (Binomial mean 32), 2x margin
#define OD_SHIFT 4    // out-degree counters padded to 64B lines (16 ints)
#define CNT_SHIFT 5   // in-degree/cursor counters padded to 128B (32 ints): these take
                      // atomic-with-return x ~32-58 per counter; packed layout put 512
                      // same-line ops -> ~307K cycle serial pole (R0 theory)

typedef short bf16x8 __attribute__((ext_vector_type(8)));
typedef float f32x4 __attribute__((ext_vector_type(4)));

static __device__ __forceinline__ unsigned short f2bf(float x) {
    __hip_bfloat16 b = __float2bfloat16(x);   // RNE
    return *reinterpret_cast<unsigned short*>(&b);
}
static __device__ __forceinline__ float bflo(unsigned int p) {
    return __uint_as_float(p << 16);
}
static __device__ __forceinline__ float bfhi(unsigned int p) {
    return __uint_as_float(p & 0xffff0000u);
}

// ---- MEGA: edge pass (atomic-bound) + feature cast + weight packs (BW-bound)
// fused in one launch so streaming waves use the HBM bandwidth the atomic
// waves leave idle. Edge blocks first so the long pole starts immediately.
// R0 change: od/cnt tables are line-padded (see OD_SHIFT/CNT_SHIFT) to kill
// same-cacheline atomic serialization.
__global__ void mega_kernel(
        // edges
        const int* __restrict__ src0, const int* __restrict__ dst0,
        int* __restrict__ od0, int* __restrict__ cnt0, int* __restrict__ esrc0, int E0,
        const int* __restrict__ src1, const int* __restrict__ dst1,
        int* __restrict__ od1, int* __restrict__ cnt1, int* __restrict__ esrc1, int E1,
        int edgeBlocks,
        // cast (raw features -> bf16, NO norm: keeps this independent of od0)
        const float* __restrict__ feat, unsigned short* __restrict__ h, int total_f,
        int castBlocks,
        // weight packs
        const float* __restrict__ W1, uint4* __restrict__ pw1,
        const float* __restrict__ W2, uint4* __restrict__ pw2) {
    const int b = blockIdx.x;
    if (b < edgeBlocks) {
        int i = b * blockDim.x + threadIdx.x;
        if (i < E0) {
            int s = src0[i];
            int d = dst0[i];
            atomicAdd(&od0[s << OD_SHIFT], 1);
            int slot = atomicAdd(&cnt0[d << CNT_SHIFT], 1);
            if (slot < RSTRIDE) esrc0[(d << 7) + slot] = s;
        } else if (i < E0 + E1) {
            int e = i - E0;
            int s = src1[e];
            int d = dst1[e];
            atomicAdd(&od1[s << OD_SHIFT], 1);
            int slot = atomicAdd(&cnt1[d << CNT_SHIFT], 1);
            if (slot < RSTRIDE) esrc1[(d << 7) + slot] = s;
        }
    } else if (b < edgeBlocks + castBlocks) {
        int idx = ((b - edgeBlocks) * blockDim.x + threadIdx.x) * 8;
        if (idx >= total_f) return;
        const float4 v0 = *reinterpret_cast<const float4*>(feat + idx);
        const float4 v1 = *reinterpret_cast<const float4*>(feat + idx + 4);
        union { ushort4 u4[2]; uint4 u; } o;
        o.u4[0].x = f2bf(v0.x); o.u4[0].y = f2bf(v0.y);
        o.u4[0].z = f2bf(v0.z); o.u4[0].w = f2bf(v0.w);
        o.u4[1].x = f2bf(v1.x); o.u4[1].y = f2bf(v1.y);
        o.u4[1].z = f2bf(v1.z); o.u4[1].w = f2bf(v1.w);
        *reinterpret_cast<uint4*>(h + idx) = o.u;
    } else if (b < edgeBlocks + castBlocks + 32) {
        // pack W1 (256x256 f32 row-major [k][n]) into bf16 B-frag layout:
        // pw[(nt*8+kt)*64+lane] = W[kt*32+(lane>>4)*8+j][nt*16+(lane&15)], j=0..7
        int idx = (b - edgeBlocks - castBlocks) * blockDim.x + threadIdx.x;   // 0..8191
        int lane = idx & 63;
        int kt = (idx >> 6) & 7;
        int nt = idx >> 9;
        int n = nt * 16 + (lane & 15);
        int k = kt * 32 + (lane >> 4) * 8;
        union { unsigned short us[8]; uint4 u; } o;
#pragma unroll
        for (int j = 0; j < 8; ++j) o.us[j] = f2bf(W1[(size_t)(k + j) * 256 + n]);
        pw1[idx] = o.u;
    } else {
        // pack W2 (256x128 f32 row-major [k][n]); 4096 frags
        int idx = (b - edgeBlocks - castBlocks - 32) * blockDim.x + threadIdx.x; // 0..4095
        int lane = idx & 63;
        int kt = (idx >> 6) & 7;
        int nt = idx >> 9;                  // 0..7
        int n = nt * 16 + (lane & 15);      // 0..127
        int k = kt * 32 + (lane >> 4) * 8;
        union { unsigned short us[8]; uint4 u; } o;
#pragma unroll
        for (int j = 0; j < 8; ++j) o.us[j] = f2bf(W2[(size_t)(k + j) * 128 + n]);
        pw2[idx] = o.u;
    }
}

// ---- bf16 gather-sum, padded CSR: one wave per dst row.
// NORM: multiply each src row by rsqrt(out_deg[src]) — od reads are wave-uniform
// loads on an L3-resident padded table. ----
template <bool NORM>
__global__ __launch_bounds__(256) void gather_bf16_kernel(
        const unsigned short* __restrict__ hfeat, const int* __restrict__ esrc,
        const int* __restrict__ cnt, const int* __restrict__ od,
        unsigned short* __restrict__ aggb, int n_dst) {
    int row = blockIdx.x * (blockDim.x >> 6) + (threadIdx.x >> 6);
    int lane = threadIdx.x & 63;
    if (row >= n_dst) return;
    const int c = cnt[row << CNT_SHIFT];
    const int cend = min(c, RSTRIDE);
    const int* __restrict__ ep = esrc + ((size_t)row << 7);
    float a0 = 0.f, a1 = 0.f, a2 = 0.f, a3 = 0.f;
    int i = 0;
    for (; i + 3 < cend; i += 4) {
        int s0 = ep[i];
        int s1 = ep[i + 1];
        int s2 = ep[i + 2];
        int s3 = ep[i + 3];
        float n0 = NORM ? rsqrtf((float)max(od[s0 << OD_SHIFT], 1)) : 1.0f;
        float n1 = NORM ? rsqrtf((float)max(od[s1 << OD_SHIFT], 1)) : 1.0f;
        float n2 = NORM ? rsqrtf((float)max(od[s2 << OD_SHIFT], 1)) : 1.0f;
        float n3 = NORM ? rsqrtf((float)max(od[s3 << OD_SHIFT], 1)) : 1.0f;
        const uint2 p0 = *reinterpret_cast<const uint2*>(hfeat + (((size_t)s0) << 8) + lane * 4);
        const uint2 p1 = *reinterpret_cast<const uint2*>(hfeat + (((size_t)s1) << 8) + lane * 4);
        const uint2 p2 = *reinterpret_cast<const uint2*>(hfeat + (((size_t)s2) << 8) + lane * 4);
        const uint2 p3 = *reinterpret_cast<const uint2*>(hfeat + (((size_t)s3) << 8) + lane * 4);
        if (NORM) {
            a0 = fmaf(bflo(p0.x), n0, a0); a1 = fmaf(bfhi(p0.x), n0, a1);
            a2 = fmaf(bflo(p0.y), n0, a2); a3 = fmaf(bfhi(p0.y), n0, a3);
            a0 = fmaf(bflo(p1.x), n1, a0); a1 = fmaf(bfhi(p1.x), n1, a1);
            a2 = fmaf(bflo(p1.y), n1, a2); a3 = fmaf(bfhi(p1.y), n1, a3);
            a0 = fmaf(bflo(p2.x), n2, a0); a1 = fmaf(bfhi(p2.x), n2, a1);
            a2 = fmaf(bflo(p2.y), n2, a2); a3 = fmaf(bfhi(p2.y), n2, a3);
            a0 = fmaf(bflo(p3.x), n3, a0); a1 = fmaf(bfhi(p3.x), n3, a1);
            a2 = fmaf(bflo(p3.y), n3, a2); a3 = fmaf(bfhi(p3.y), n3, a3);
        } else {
            a0 += (bflo(p0.x) + bflo(p1.x)) + (bflo(p2.x) + bflo(p3.x));
            a1 += (bfhi(p0.x) + bfhi(p1.x)) + (bfhi(p2.x) + bfhi(p3.x));
            a2 += (bflo(p0.y) + bflo(p1.y)) + (bflo(p2.y) + bflo(p3.y));
            a3 += (bfhi(p0.y) + bfhi(p1.y)) + (bfhi(p2.y) + bfhi(p3.y));
        }
    }
    for (; i < cend; ++i) {
        int s0 = ep[i];
        float n0 = NORM ? rsqrtf((float)max(od[s0 << OD_SHIFT], 1)) : 1.0f;
        const uint2 p0 = *reinterpret_cast<const uint2*>(hfeat + (((size_t)s0) << 8) + lane * 4);
        if (NORM) {
            a0 = fmaf(bflo(p0.x), n0, a0); a1 = fmaf(bfhi(p0.x), n0, a1);
            a2 = fmaf(bflo(p0.y), n0, a2); a3 = fmaf(bfhi(p0.y), n0, a3);
        } else {
            a0 += bflo(p0.x);
            a1 += bfhi(p0.x);
            a2 += bflo(p0.y);
            a3 += bfhi(p0.y);
        }
    }
    float nd = rsqrtf((float)max(c, 1));
    ushort4 o;
    o.x = f2bf(a0 * nd);
    o.y = f2bf(a1 * nd);
    o.z = f2bf(a2 * nd);
    o.w = f2bf(a3 * nd);
    *reinterpret_cast<ushort4*>(aggb + (((size_t)row) << 8) + lane * 4) = o;
}

// ---- MFMA GEMM layer 0: xbuf(bf16) = relu(hA @ W1 + b1) * rsqrt(od1[row]) ----
// Block = 16-row M-tile; 4 waves x 4 n-tiles = 256 cols. C/D: col=lane&15, row=(lane>>4)*4+reg.
__global__ __launch_bounds__(256) void gemm0_mfma_kernel(
        const unsigned short* __restrict__ hA, const uint4* __restrict__ pW,
        const float* __restrict__ bias, const int* __restrict__ od1,
        unsigned short* __restrict__ out, int M) {
    const int m0 = blockIdx.x * 16;
    const int w = threadIdx.x >> 6;
    const int lane = threadIdx.x & 63;

    bf16x8 a[8];
    const unsigned short* ap = hA + (size_t)(m0 + (lane & 15)) * K_DIM + (lane >> 4) * 8;
#pragma unroll
    for (int kt = 0; kt < 8; ++kt)
        a[kt] = *reinterpret_cast<const bf16x8*>(ap + kt * 32);

    const int rbase = m0 + (lane >> 4) * 4;
    float nsv[4];
#pragma unroll
    for (int r = 0; r < 4; ++r) nsv[r] = rsqrtf((float)max(od1[(rbase + r) << OD_SHIFT], 1));

#pragma unroll
    for (int nt = 0; nt < 4; ++nt) {
        const int n0 = w * 64 + nt * 16;
        f32x4 acc = {0.f, 0.f, 0.f, 0.f};
#pragma unroll
        for (int kt = 0; kt < 8; ++kt) {
            bf16x8 b = *reinterpret_cast<const bf16x8*>(&pW[((size_t)(n0 >> 4) * 8 + kt) * 64 + lane]);
            acc = __builtin_amdgcn_mfma_f32_16x16x32_bf16(a[kt], b, acc, 0, 0, 0);
        }
        const int col = n0 + (lane & 15);
        const float bv = bias[col];
#pragma unroll
        for (int r = 0; r < 4; ++r) {
            float v = fmaxf(acc[r] + bv, 0.0f) * nsv[r];
            out[(size_t)(rbase + r) * K_DIM + col] = f2bf(v);
        }
    }
}

// ---- MFMA GEMM layer 2: d_out(f32) = hA @ W2 + b2; N=128 (4 waves x 2 n-tiles) ----
__global__ __launch_bounds__(256) void gemm1_mfma_kernel(
        const unsigned short* __restrict__ hA, const uint4* __restrict__ pW,
        const float* __restrict__ bias, float* __restrict__ out, int M) {
    const int m0 = blockIdx.x * 16;
    const int w = threadIdx.x >> 6;
    const int lane = threadIdx.x & 63;

    bf16x8 a[8];
    const unsigned short* ap = hA + (size_t)(m0 + (lane & 15)) * K_DIM + (lane >> 4) * 8;
#pragma unroll
    for (int kt = 0; kt < 8; ++kt)
        a[kt] = *reinterpret_cast<const bf16x8*>(ap + kt * 32);

    const int rbase = m0 + (lane >> 4) * 4;
#pragma unroll
    for (int nt = 0; nt < 2; ++nt) {
        const int n0 = w * 32 + nt * 16;
        f32x4 acc = {0.f, 0.f, 0.f, 0.f};
#pragma unroll
        for (int kt = 0; kt < 8; ++kt) {
            bf16x8 b = *reinterpret_cast<const bf16x8*>(&pW[((size_t)(n0 >> 4) * 8 + kt) * 64 + lane]);
            acc = __builtin_amdgcn_mfma_f32_16x16x32_bf16(a[kt], b, acc, 0, 0, 0);
        }
        const int col = n0 + (lane & 15);
        const float bv = bias[col];
#pragma unroll
        for (int r = 0; r < 4; ++r)
            out[(size_t)(rbase + r) * 128 + col] = acc[r] + bv;
    }
}

// ---- fp32 padded gather with per-edge src norm (fallback path only) ----
__global__ __launch_bounds__(256) void gatherf_kernel(
        const float* __restrict__ feat, const int* __restrict__ esrc,
        const int* __restrict__ cnt, const int* __restrict__ od,
        float* __restrict__ outbuf, int n_dst) {
    int row = blockIdx.x * (blockDim.x >> 6) + (threadIdx.x >> 6);
    int lane = threadIdx.x & 63;
    if (row >= n_dst) return;
    const int c = cnt[row << CNT_SHIFT];
    const int cend = min(c, RSTRIDE);
    const int* __restrict__ ep = esrc + ((size_t)row << 7);
    float4 acc = {0.f, 0.f, 0.f, 0.f};
    for (int i = 0; i < cend; ++i) {
        int s0 = ep[i];
        float n0 = rsqrtf((float)max(od[s0 << OD_SHIFT], 1));
        const float4 v0 = *reinterpret_cast<const float4*>(feat + (((size_t)s0) << 8) + lane * 4);
        acc.x = fmaf(v0.x, n0, acc.x); acc.y = fmaf(v0.y, n0, acc.y);
        acc.z = fmaf(v0.z, n0, acc.z); acc.w = fmaf(v0.w, n0, acc.w);
    }
    float nd = rsqrtf((float)max(c, 1));
    float4 o = {acc.x * nd, acc.y * nd, acc.z * nd, acc.w * nd};
    *reinterpret_cast<float4*>(outbuf + (((size_t)row) << 8) + lane * 4) = o;
}

// ---- fallback-only: edge pass without the fused streaming work ----
__global__ void edges_kernel(const int* __restrict__ src0, const int* __restrict__ dst0,
                             int* __restrict__ od0, int* __restrict__ cnt0,
                             int* __restrict__ esrc0, int E0,
                             const int* __restrict__ src1, const int* __restrict__ dst1,
                             int* __restrict__ od1, int* __restrict__ cnt1,
                             int* __restrict__ esrc1, int E1) {
    int i = blockIdx.x * blockDim.x + threadIdx.x;
    if (i < E0) {
        int s = src0[i];
        int d = dst0[i];
        atomicAdd(&od0[s << OD_SHIFT], 1);
        int slot = atomicAdd(&cnt0[d << CNT_SHIFT], 1);
        if (slot < RSTRIDE) esrc0[(d << 7) + slot] = s;
    } else if (i < E0 + E1) {
        int e = i - E0;
        int s = src1[e];
        int d = dst1[e];
        atomicAdd(&od1[s << OD_SHIFT], 1);
        int slot = atomicAdd(&cnt1[d << CNT_SHIFT], 1);
        if (slot < RSTRIDE) esrc1[(d << 7) + slot] = s;
    }
}

// ---- vector GEMM (fallback only) ----
template <int ROWS, int NCOLS, bool RELU>
__global__ __launch_bounds__(NCOLS) void gemm_kernel(
        const float* __restrict__ A, const float* __restrict__ W,
        const float* __restrict__ bias, float* __restrict__ out, int M) {
    const int row0 = blockIdx.x * ROWS;
    const int c = threadIdx.x;
    const float* __restrict__ Ablk = A + (size_t)row0 * K_DIM;
    const float* __restrict__ Wc = W + c;

    float acc[ROWS];
#pragma unroll
    for (int r = 0; r < ROWS; ++r) acc[r] = 0.0f;

    float w0 = Wc[0];
    float w1 = Wc[NCOLS];
    float w2 = Wc[2 * NCOLS];
    float w3 = Wc[3 * NCOLS];

#pragma unroll 2
    for (int k = 0; k < K_DIM - 4; k += 4) {
        const float* p = Wc + (size_t)(k + 4) * NCOLS;
        float n0 = p[0];
        float n1 = p[NCOLS];
        float n2 = p[2 * NCOLS];
        float n3 = p[3 * NCOLS];
#pragma unroll
        for (int r = 0; r < ROWS; ++r) {
            const float4 a = *reinterpret_cast<const float4*>(Ablk + r * K_DIM + k);
            acc[r] = fmaf(a.x, w0, acc[r]);
            acc[r] = fmaf(a.y, w1, acc[r]);
            acc[r] = fmaf(a.z, w2, acc[r]);
            acc[r] = fmaf(a.w, w3, acc[r]);
        }
        w0 = n0; w1 = n1; w2 = n2; w3 = n3;
    }
    {
        const int k = K_DIM - 4;
#pragma unroll
        for (int r = 0; r < ROWS; ++r) {
            const float4 a = *reinterpret_cast<const float4*>(Ablk + r * K_DIM + k);
            acc[r] = fmaf(a.x, w0, acc[r]);
            acc[r] = fmaf(a.y, w1, acc[r]);
            acc[r] = fmaf(a.z, w2, acc[r]);
            acc[r] = fmaf(a.w, w3, acc[r]);
        }
    }

    const float b = bias[c];
#pragma unroll
    for (int r = 0; r < ROWS; ++r) {
        float v = acc[r] + b;
        if (RELU) v = fmaxf(v, 0.0f);
        out[(size_t)(row0 + r) * NCOLS + c] = v;
    }
}

extern "C" void kernel_launch(void* const* d_in, const int* in_sizes, int n_in,
                              void* d_out, int out_size, void* d_ws, size_t ws_size,
                              hipStream_t stream) {
    const float* features = (const float*)d_in[0];
    const float* W1 = (const float*)d_in[1];
    const float* b1 = (const float*)d_in[2];
    const float* W2 = (const float*)d_in[3];
    const float* b2 = (const float*)d_in[4];
    const int* src0 = (const int*)d_in[5];
    const int* dst0 = (const int*)d_in[6];
    const int* src1 = (const int*)d_in[7];
    const int* dst1 = (const int*)d_in[8];
    const int E0 = in_sizes[5];
    const int E1 = in_sizes[7];
    const int NSRC0 = 100000, NDST0 = 20000, NDST1 = 4096;

    char* ws = (char*)d_ws;
    size_t off = 0;
    auto carve = [&](size_t bytes) -> void* {
        void* p = ws + off;
        off = (off + bytes + 255) & ~(size_t)255;
        return p;
    };
    // zero-init region first (one contiguous memset): padded out-degs + padded cursors
    int* od0  = (int*)carve((size_t)NSRC0 * 4 << OD_SHIFT);    // 6.4 MB
    int* od1  = (int*)carve((size_t)NDST0 * 4 << OD_SHIFT);    // 1.28 MB
    int* cnt0 = (int*)carve((size_t)NDST0 * 4 << CNT_SHIFT);   // 2.56 MB
    int* cnt1 = (int*)carve((size_t)NDST1 * 4 << CNT_SHIFT);   // 0.52 MB
    const size_t zero_span = off;
    uint4* pW1  = (uint4*)carve((size_t)8192 * 16);
    uint4* pW2  = (uint4*)carve((size_t)4096 * 16);
    int* esrc0p = (int*)carve((size_t)NDST0 * RSTRIDE * 4);
    int* esrc1p = (int*)carve((size_t)NDST1 * RSTRIDE * 4);
    unsigned short* aggb = (unsigned short*)carve((size_t)NDST0 * K_DIM * 2);
    const size_t hfeat_bytes = (size_t)NSRC0 * K_DIM * 2;
    const size_t xbufb_bytes = (size_t)NDST0 * K_DIM * 2;
    const size_t agg1b_bytes = (size_t)NDST1 * K_DIM * 2;
    const size_t need_bf16 = off + (hfeat_bytes > xbufb_bytes + agg1b_bytes
                                        ? hfeat_bytes : xbufb_bytes + agg1b_bytes);
    (void)n_in; (void)out_size;

    hipMemsetAsync(ws, 0, zero_span, stream);

    if (ws_size >= need_bf16) {
        unsigned short* hfeat = (unsigned short*)(ws + off);
        unsigned short* xbufb = (unsigned short*)(ws + off);   // alias: hfeat dead after gather0
        unsigned short* agg1b = (unsigned short*)(ws + off + xbufb_bytes);

        const int total_f = NSRC0 * K_DIM;
        const int edgeBlocks = (E0 + E1 + 255) / 256;        // 3013
        const int castBlocks = (total_f / 8 + 255) / 256;    // 12500
        mega_kernel<<<edgeBlocks + castBlocks + 48, 256, 0, stream>>>(
            src0, dst0, od0, cnt0, esrc0p, E0,
            src1, dst1, od1, cnt1, esrc1p, E1, edgeBlocks,
            features, hfeat, total_f, castBlocks,
            W1, pW1, W2, pW2);
        gather_bf16_kernel<true><<<(NDST0 + 3) / 4, 256, 0, stream>>>(
            hfeat, esrc0p, cnt0, od0, aggb, NDST0);
        gemm0_mfma_kernel<<<NDST0 / 16, 256, 0, stream>>>(aggb, pW1, b1, od1, xbufb, NDST0);
        gather_bf16_kernel<false><<<(NDST1 + 3) / 4, 256, 0, stream>>>(
            xbufb, esrc1p, cnt1, nullptr, agg1b, NDST1);
        gemm1_mfma_kernel<<<NDST1 / 16, 256, 0, stream>>>(agg1b, pW2, b2,
                                                          (float*)d_out, NDST1);
    } else {
        // fp32 fallback
        float* agg0 = (float*)carve((size_t)NDST0 * K_DIM * 4);
        float* xbuf = (float*)carve((size_t)NDST0 * K_DIM * 4);
        float* agg1 = (float*)carve((size_t)NDST1 * K_DIM * 4);
        edges_kernel<<<(E0 + E1 + 255) / 256, 256, 0, stream>>>(
            src0, dst0, od0, cnt0, esrc0p, E0,
            src1, dst1, od1, cnt1, esrc1p, E1);
        gatherf_kernel<<<(NDST0 + 3) / 4, 256, 0, stream>>>(features, esrc0p, cnt0, od0,
                                                            agg0, NDST0);
        gemm_kernel<16, 256, true><<<NDST0 / 16, 256, 0, stream>>>(agg0, W1, b1, xbuf, NDST0);
        gatherf_kernel<<<(NDST1 + 3) / 4, 256, 0, stream>>>(xbuf, esrc1p, cnt1, od1,
                                                            agg1, NDST1);
        gemm_kernel<4, 128, false><<<NDST1 / 4, 128, 0, stream>>>(agg1, W2, b2,
                                                                  (float*)d_out, NDST1);
    }
}

// Round 2
// 283.110 us; speedup vs baseline: 1.1554x; 1.1500x over previous
//
#include <hip/hip_runtime.h>
#include <hip/hip_bf16.h>

#define K_DIM 256
#define RSTRIDE 128   // padded CSR row stride; in-deg max ~58 (Binomial mean 32), 2x margin

// ---- multi-split geometry (R2): replace 1.54M memory-side atomics with ~72K
// block-aggregated reservations. Capacities are mean + >30 sigma.
#define EPB   8192    // edges per split block
#define G0_DB 625     // graph0 dst buckets (32 dsts each, 625*32 = 20000)
#define G0_SB 256     // graph0 src buckets (392 nodes each, covers 100352)
#define G0_SW 392
#define G1_DB 128     // graph1 dst buckets (32 dsts each, 128*32 = 4096)
#define G1_SB 64      // graph1 src buckets (313 nodes each, covers 20032)
#define G1_SW 313
#define BCAP  2048    // dst-bucket capacity (mean 1024, sigma 32)
#define SCAP  4096    // src-bucket capacity (mean 2500/2048, sigma ~50)
#define GPAD  16      // global bucket-cursor padding (ints, 64B lines)

typedef short bf16x8 __attribute__((ext_vector_type(8)));
typedef float f32x4 __attribute__((ext_vector_type(4)));

static __device__ __forceinline__ unsigned short f2bf(float x) {
    __hip_bfloat16 b = __float2bfloat16(x);   // RNE
    return *reinterpret_cast<unsigned short*>(&b);
}
static __device__ __forceinline__ float bflo(unsigned int p) {
    return __uint_as_float(p << 16);
}
static __device__ __forceinline__ float bfhi(unsigned int p) {
    return __uint_as_float(p & 0xffff0000u);
}

// ---- block-privatized multi-split: per 8192-edge chunk, LDS-histogram both
// keyings (dst-bucket for CSR build, src-bucket for out-degree), reserve global
// ranges with ONE returning atomic per touched bucket, scatter packed edges.
template <int NDB, int NSB, int SW>
static __device__ __forceinline__ void split_graph(
        const int* __restrict__ src, const int* __restrict__ dst, int E, int chunk,
        int* __restrict__ gdc, int* __restrict__ gsc,
        unsigned int* __restrict__ bdst, unsigned int* __restrict__ bsrc,
        int* sh) {
    int* histD = sh;
    int* histS = sh + NDB;
    int* baseD = sh + NDB + NSB;
    int* baseS = baseD + NDB;
    const int tid = threadIdx.x;
    const int e0 = chunk * EPB;
    const int n = min(EPB, E - e0);
    for (int i = tid; i < NDB + NSB; i += 256) sh[i] = 0;
    __syncthreads();
    for (int j = tid; j < n; j += 256) {
        int d = dst[e0 + j];
        int s = src[e0 + j];
        atomicAdd(&histD[d >> 5], 1);
        atomicAdd(&histS[(int)((unsigned)s / SW)], 1);
    }
    __syncthreads();
    for (int i = tid; i < NDB; i += 256) {
        int h = histD[i];
        baseD[i] = h ? atomicAdd(&gdc[i * GPAD], h) : 0;   // one global atomic / bucket
        histD[i] = 0;                                      // reuse as pass-2 cursor
    }
    for (int i = tid; i < NSB; i += 256) {
        int h = histS[i];
        baseS[i] = h ? atomicAdd(&gsc[i * GPAD], h) : 0;
        histS[i] = 0;
    }
    __syncthreads();
    for (int j = tid; j < n; j += 256) {
        int d = dst[e0 + j];
        int s = src[e0 + j];
        int bD = d >> 5;
        int rD = atomicAdd(&histD[bD], 1) + baseD[bD];
        if (rD < BCAP) bdst[(size_t)bD * BCAP + rD] = ((unsigned)s << 5) | (unsigned)(d & 31);
        int bS = (int)((unsigned)s / SW);
        int rS = atomicAdd(&histS[bS], 1) + baseS[bS];
        if (rS < SCAP) bsrc[(size_t)bS * SCAP + rS] = (unsigned)s;
    }
}

// ---- MEGA: edge multi-split (graph0 + graph1) + feature cast + weight packs.
// Split blocks first; cast blocks stream concurrently.
__global__ __launch_bounds__(256) void split_mega_kernel(
        const int* __restrict__ src0, const int* __restrict__ dst0, int E0,
        const int* __restrict__ src1, const int* __restrict__ dst1, int E1,
        int* __restrict__ gdc0, int* __restrict__ gsc0,
        unsigned int* __restrict__ bdst0, unsigned int* __restrict__ bsrc0,
        int* __restrict__ gdc1, int* __restrict__ gsc1,
        unsigned int* __restrict__ bdst1, unsigned int* __restrict__ bsrc1,
        int nA0, int nA1,
        const float* __restrict__ feat, unsigned short* __restrict__ h, int total_f,
        int castBlocks,
        const float* __restrict__ W1, uint4* __restrict__ pw1,
        const float* __restrict__ W2, uint4* __restrict__ pw2) {
    __shared__ int sh[2 * (G0_DB + G0_SB)];
    const int b = blockIdx.x;
    if (b < nA0) {
        split_graph<G0_DB, G0_SB, G0_SW>(src0, dst0, E0, b, gdc0, gsc0, bdst0, bsrc0, sh);
    } else if (b < nA0 + nA1) {
        split_graph<G1_DB, G1_SB, G1_SW>(src1, dst1, E1, b - nA0, gdc1, gsc1, bdst1, bsrc1, sh);
    } else if (b < nA0 + nA1 + castBlocks) {
        int idx = ((b - nA0 - nA1) * blockDim.x + threadIdx.x) * 8;
        if (idx >= total_f) return;
        const float4 v0 = *reinterpret_cast<const float4*>(feat + idx);
        const float4 v1 = *reinterpret_cast<const float4*>(feat + idx + 4);
        union { ushort4 u4[2]; uint4 u; } o;
        o.u4[0].x = f2bf(v0.x); o.u4[0].y = f2bf(v0.y);
        o.u4[0].z = f2bf(v0.z); o.u4[0].w = f2bf(v0.w);
        o.u4[1].x = f2bf(v1.x); o.u4[1].y = f2bf(v1.y);
        o.u4[1].z = f2bf(v1.z); o.u4[1].w = f2bf(v1.w);
        *reinterpret_cast<uint4*>(h + idx) = o.u;
    } else if (b < nA0 + nA1 + castBlocks + 32) {
        // pack W1 (256x256 f32 [k][n]) -> bf16 B-frag layout:
        // pw[(nt*8+kt)*64+lane] = W[kt*32+(lane>>4)*8+j][nt*16+(lane&15)], j=0..7
        int idx = (b - nA0 - nA1 - castBlocks) * blockDim.x + threadIdx.x;   // 0..8191
        int lane = idx & 63;
        int kt = (idx >> 6) & 7;
        int nt = idx >> 9;
        int n = nt * 16 + (lane & 15);
        int k = kt * 32 + (lane >> 4) * 8;
        union { unsigned short us[8]; uint4 u; } o;
#pragma unroll
        for (int j = 0; j < 8; ++j) o.us[j] = f2bf(W1[(size_t)(k + j) * 256 + n]);
        pw1[idx] = o.u;
    } else {
        int idx = (b - nA0 - nA1 - castBlocks - 32) * blockDim.x + threadIdx.x; // 0..4095
        int lane = idx & 63;
        int kt = (idx >> 6) & 7;
        int nt = idx >> 9;
        int n = nt * 16 + (lane & 15);
        int k = kt * 32 + (lane >> 4) * 8;
        union { unsigned short us[8]; uint4 u; } o;
#pragma unroll
        for (int j = 0; j < 8; ++j) o.us[j] = f2bf(W2[(size_t)(k + j) * 128 + n]);
        pw2[idx] = o.u;
    }
}

// ---- finalize: per-bucket CSR build (LDS cursors -> padded esrc + dense cnt)
// and per-bucket out-degree histogram (LDS -> dense od, zeros included).
__global__ __launch_bounds__(256) void finalize_kernel(
        const unsigned int* __restrict__ bdst0, const int* __restrict__ gdc0,
        int* __restrict__ cnt0, int* __restrict__ esrc0,
        const unsigned int* __restrict__ bdst1, const int* __restrict__ gdc1,
        int* __restrict__ cnt1, int* __restrict__ esrc1,
        const unsigned int* __restrict__ bsrc0, const int* __restrict__ gsc0,
        int* __restrict__ od0,
        const unsigned int* __restrict__ bsrc1, const int* __restrict__ gsc1,
        int* __restrict__ od1) {
    __shared__ int sh[G0_SW];
    const int tid = threadIdx.x;
    int b = blockIdx.x;
    if (b < G0_DB + G1_DB) {
        const bool g0 = b < G0_DB;
        if (!g0) b -= G0_DB;
        const unsigned int* __restrict__ bd = g0 ? bdst0 : bdst1;
        const int nb = min((g0 ? gdc0 : gdc1)[b * GPAD], BCAP);
        int* __restrict__ esrc = g0 ? esrc0 : esrc1;
        int* __restrict__ cnt = g0 ? cnt0 : cnt1;
        if (tid < 32) sh[tid] = 0;
        __syncthreads();
        for (int j = tid; j < nb; j += 256) {
            unsigned v = bd[(size_t)b * BCAP + j];
            int dloc = v & 31;
            int s = v >> 5;
            int slot = atomicAdd(&sh[dloc], 1);
            if (slot < RSTRIDE) esrc[((size_t)(b * 32 + dloc) << 7) + slot] = s;
        }
        __syncthreads();
        if (tid < 32) cnt[b * 32 + tid] = sh[tid];
    } else {
        b -= G0_DB + G1_DB;
        const bool g0 = b < G0_SB;
        if (!g0) b -= G0_SB;
        const unsigned int* __restrict__ bs = g0 ? bsrc0 : bsrc1;
        const int SW = g0 ? G0_SW : G1_SW;
        const int NN = g0 ? 100000 : 20000;
        const int nb = min((g0 ? gsc0 : gsc1)[b * GPAD], SCAP);
        int* __restrict__ od = g0 ? od0 : od1;
        for (int i = tid; i < SW; i += 256) sh[i] = 0;
        __syncthreads();
        const int base = b * SW;
        for (int j = tid; j < nb; j += 256) {
            int v = (int)bs[(size_t)b * SCAP + j];
            atomicAdd(&sh[v - base], 1);
        }
        __syncthreads();
        for (int i = tid; i < SW; i += 256) {
            int node = base + i;
            if (node < NN) od[node] = sh[i];
        }
    }
}

// ---- bf16 gather-sum, padded CSR: one wave per dst row. Dense cnt/od tables. ----
template <bool NORM>
__global__ __launch_bounds__(256) void gather_bf16_kernel(
        const unsigned short* __restrict__ hfeat, const int* __restrict__ esrc,
        const int* __restrict__ cnt, const int* __restrict__ od,
        unsigned short* __restrict__ aggb, int n_dst) {
    int row = blockIdx.x * (blockDim.x >> 6) + (threadIdx.x >> 6);
    int lane = threadIdx.x & 63;
    if (row >= n_dst) return;
    const int c = cnt[row];
    const int cend = min(c, RSTRIDE);
    const int* __restrict__ ep = esrc + ((size_t)row << 7);
    float a0 = 0.f, a1 = 0.f, a2 = 0.f, a3 = 0.f;
    int i = 0;
    for (; i + 3 < cend; i += 4) {
        int s0 = ep[i];
        int s1 = ep[i + 1];
        int s2 = ep[i + 2];
        int s3 = ep[i + 3];
        float n0 = NORM ? rsqrtf((float)max(od[s0], 1)) : 1.0f;
        float n1 = NORM ? rsqrtf((float)max(od[s1], 1)) : 1.0f;
        float n2 = NORM ? rsqrtf((float)max(od[s2], 1)) : 1.0f;
        float n3 = NORM ? rsqrtf((float)max(od[s3], 1)) : 1.0f;
        const uint2 p0 = *reinterpret_cast<const uint2*>(hfeat + (((size_t)s0) << 8) + lane * 4);
        const uint2 p1 = *reinterpret_cast<const uint2*>(hfeat + (((size_t)s1) << 8) + lane * 4);
        const uint2 p2 = *reinterpret_cast<const uint2*>(hfeat + (((size_t)s2) << 8) + lane * 4);
        const uint2 p3 = *reinterpret_cast<const uint2*>(hfeat + (((size_t)s3) << 8) + lane * 4);
        if (NORM) {
            a0 = fmaf(bflo(p0.x), n0, a0); a1 = fmaf(bfhi(p0.x), n0, a1);
            a2 = fmaf(bflo(p0.y), n0, a2); a3 = fmaf(bfhi(p0.y), n0, a3);
            a0 = fmaf(bflo(p1.x), n1, a0); a1 = fmaf(bfhi(p1.x), n1, a1);
            a2 = fmaf(bflo(p1.y), n1, a2); a3 = fmaf(bfhi(p1.y), n1, a3);
            a0 = fmaf(bflo(p2.x), n2, a0); a1 = fmaf(bfhi(p2.x), n2, a1);
            a2 = fmaf(bflo(p2.y), n2, a2); a3 = fmaf(bfhi(p2.y), n2, a3);
            a0 = fmaf(bflo(p3.x), n3, a0); a1 = fmaf(bfhi(p3.x), n3, a1);
            a2 = fmaf(bflo(p3.y), n3, a2); a3 = fmaf(bfhi(p3.y), n3, a3);
        } else {
            a0 += (bflo(p0.x) + bflo(p1.x)) + (bflo(p2.x) + bflo(p3.x));
            a1 += (bfhi(p0.x) + bfhi(p1.x)) + (bfhi(p2.x) + bfhi(p3.x));
            a2 += (bflo(p0.y) + bflo(p1.y)) + (bflo(p2.y) + bflo(p3.y));
            a3 += (bfhi(p0.y) + bfhi(p1.y)) + (bfhi(p2.y) + bfhi(p3.y));
        }
    }
    for (; i < cend; ++i) {
        int s0 = ep[i];
        float n0 = NORM ? rsqrtf((float)max(od[s0], 1)) : 1.0f;
        const uint2 p0 = *reinterpret_cast<const uint2*>(hfeat + (((size_t)s0) << 8) + lane * 4);
        if (NORM) {
            a0 = fmaf(bflo(p0.x), n0, a0); a1 = fmaf(bfhi(p0.x), n0, a1);
            a2 = fmaf(bflo(p0.y), n0, a2); a3 = fmaf(bfhi(p0.y), n0, a3);
        } else {
            a0 += bflo(p0.x);
            a1 += bfhi(p0.x);
            a2 += bflo(p0.y);
            a3 += bfhi(p0.y);
        }
    }
    float nd = rsqrtf((float)max(c, 1));
    ushort4 o;
    o.x = f2bf(a0 * nd);
    o.y = f2bf(a1 * nd);
    o.z = f2bf(a2 * nd);
    o.w = f2bf(a3 * nd);
    *reinterpret_cast<ushort4*>(aggb + (((size_t)row) << 8) + lane * 4) = o;
}

// ---- MFMA GEMM layer 0: xbuf(bf16) = relu(hA @ W1 + b1) * rsqrt(od1[row]) ----
__global__ __launch_bounds__(256) void gemm0_mfma_kernel(
        const unsigned short* __restrict__ hA, const uint4* __restrict__ pW,
        const float* __restrict__ bias, const int* __restrict__ od1,
        unsigned short* __restrict__ out, int M) {
    const int m0 = blockIdx.x * 16;
    const int w = threadIdx.x >> 6;
    const int lane = threadIdx.x & 63;

    bf16x8 a[8];
    const unsigned short* ap = hA + (size_t)(m0 + (lane & 15)) * K_DIM + (lane >> 4) * 8;
#pragma unroll
    for (int kt = 0; kt < 8; ++kt)
        a[kt] = *reinterpret_cast<const bf16x8*>(ap + kt * 32);

    const int rbase = m0 + (lane >> 4) * 4;
    float nsv[4];
#pragma unroll
    for (int r = 0; r < 4; ++r) nsv[r] = rsqrtf((float)max(od1[rbase + r], 1));

#pragma unroll
    for (int nt = 0; nt < 4; ++nt) {
        const int n0 = w * 64 + nt * 16;
        f32x4 acc = {0.f, 0.f, 0.f, 0.f};
#pragma unroll
        for (int kt = 0; kt < 8; ++kt) {
            bf16x8 b = *reinterpret_cast<const bf16x8*>(&pW[((size_t)(n0 >> 4) * 8 + kt) * 64 + lane]);
            acc = __builtin_amdgcn_mfma_f32_16x16x32_bf16(a[kt], b, acc, 0, 0, 0);
        }
        const int col = n0 + (lane & 15);
        const float bv = bias[col];
#pragma unroll
        for (int r = 0; r < 4; ++r) {
            float v = fmaxf(acc[r] + bv, 0.0f) * nsv[r];
            out[(size_t)(rbase + r) * K_DIM + col] = f2bf(v);
        }
    }
}

// ---- MFMA GEMM layer 2: d_out(f32) = hA @ W2 + b2 ----
__global__ __launch_bounds__(256) void gemm1_mfma_kernel(
        const unsigned short* __restrict__ hA, const uint4* __restrict__ pW,
        const float* __restrict__ bias, float* __restrict__ out, int M) {
    const int m0 = blockIdx.x * 16;
    const int w = threadIdx.x >> 6;
    const int lane = threadIdx.x & 63;

    bf16x8 a[8];
    const unsigned short* ap = hA + (size_t)(m0 + (lane & 15)) * K_DIM + (lane >> 4) * 8;
#pragma unroll
    for (int kt = 0; kt < 8; ++kt)
        a[kt] = *reinterpret_cast<const bf16x8*>(ap + kt * 32);

    const int rbase = m0 + (lane >> 4) * 4;
#pragma unroll
    for (int nt = 0; nt < 2; ++nt) {
        const int n0 = w * 32 + nt * 16;
        f32x4 acc = {0.f, 0.f, 0.f, 0.f};
#pragma unroll
        for (int kt = 0; kt < 8; ++kt) {
            bf16x8 b = *reinterpret_cast<const bf16x8*>(&pW[((size_t)(n0 >> 4) * 8 + kt) * 64 + lane]);
            acc = __builtin_amdgcn_mfma_f32_16x16x32_bf16(a[kt], b, acc, 0, 0, 0);
        }
        const int col = n0 + (lane & 15);
        const float bv = bias[col];
#pragma unroll
        for (int r = 0; r < 4; ++r)
            out[(size_t)(rbase + r) * 128 + col] = acc[r] + bv;
    }
}

// ---- fp32 padded gather (fallback path only) ----
__global__ __launch_bounds__(256) void gatherf_kernel(
        const float* __restrict__ feat, const int* __restrict__ esrc,
        const int* __restrict__ cnt, const int* __restrict__ od,
        float* __restrict__ outbuf, int n_dst) {
    int row = blockIdx.x * (blockDim.x >> 6) + (threadIdx.x >> 6);
    int lane = threadIdx.x & 63;
    if (row >= n_dst) return;
    const int c = cnt[row];
    const int cend = min(c, RSTRIDE);
    const int* __restrict__ ep = esrc + ((size_t)row << 7);
    float4 acc = {0.f, 0.f, 0.f, 0.f};
    for (int i = 0; i < cend; ++i) {
        int s0 = ep[i];
        float n0 = rsqrtf((float)max(od[s0], 1));
        const float4 v0 = *reinterpret_cast<const float4*>(feat + (((size_t)s0) << 8) + lane * 4);
        acc.x = fmaf(v0.x, n0, acc.x); acc.y = fmaf(v0.y, n0, acc.y);
        acc.z = fmaf(v0.z, n0, acc.z); acc.w = fmaf(v0.w, n0, acc.w);
    }
    float nd = rsqrtf((float)max(c, 1));
    float4 o = {acc.x * nd, acc.y * nd, acc.z * nd, acc.w * nd};
    *reinterpret_cast<float4*>(outbuf + (((size_t)row) << 8) + lane * 4) = o;
}

// ---- fallback-only: direct-atomic edge pass (dense od/cnt) ----
__global__ void edges_kernel(const int* __restrict__ src0, const int* __restrict__ dst0,
                             int* __restrict__ od0, int* __restrict__ cnt0,
                             int* __restrict__ esrc0, int E0,
                             const int* __restrict__ src1, const int* __restrict__ dst1,
                             int* __restrict__ od1, int* __restrict__ cnt1,
                             int* __restrict__ esrc1, int E1) {
    int i = blockIdx.x * blockDim.x + threadIdx.x;
    if (i < E0) {
        int s = src0[i];
        int d = dst0[i];
        atomicAdd(&od0[s], 1);
        int slot = atomicAdd(&cnt0[d], 1);
        if (slot < RSTRIDE) esrc0[(d << 7) + slot] = s;
    } else if (i < E0 + E1) {
        int e = i - E0;
        int s = src1[e];
        int d = dst1[e];
        atomicAdd(&od1[s], 1);
        int slot = atomicAdd(&cnt1[d], 1);
        if (slot < RSTRIDE) esrc1[(d << 7) + slot] = s;
    }
}

// ---- vector GEMM (fallback only) ----
template <int ROWS, int NCOLS, bool RELU>
__global__ __launch_bounds__(NCOLS) void gemm_kernel(
        const float* __restrict__ A, const float* __restrict__ W,
        const float* __restrict__ bias, float* __restrict__ out, int M) {
    const int row0 = blockIdx.x * ROWS;
    const int c = threadIdx.x;
    const float* __restrict__ Ablk = A + (size_t)row0 * K_DIM;
    const float* __restrict__ Wc = W + c;

    float acc[ROWS];
#pragma unroll
    for (int r = 0; r < ROWS; ++r) acc[r] = 0.0f;

    float w0 = Wc[0];
    float w1 = Wc[NCOLS];
    float w2 = Wc[2 * NCOLS];
    float w3 = Wc[3 * NCOLS];

#pragma unroll 2
    for (int k = 0; k < K_DIM - 4; k += 4) {
        const float* p = Wc + (size_t)(k + 4) * NCOLS;
        float n0 = p[0];
        float n1 = p[NCOLS];
        float n2 = p[2 * NCOLS];
        float n3 = p[3 * NCOLS];
#pragma unroll
        for (int r = 0; r < ROWS; ++r) {
            const float4 a = *reinterpret_cast<const float4*>(Ablk + r * K_DIM + k);
            acc[r] = fmaf(a.x, w0, acc[r]);
            acc[r] = fmaf(a.y, w1, acc[r]);
            acc[r] = fmaf(a.z, w2, acc[r]);
            acc[r] = fmaf(a.w, w3, acc[r]);
        }
        w0 = n0; w1 = n1; w2 = n2; w3 = n3;
    }
    {
        const int k = K_DIM - 4;
#pragma unroll
        for (int r = 0; r < ROWS; ++r) {
            const float4 a = *reinterpret_cast<const float4*>(Ablk + r * K_DIM + k);
            acc[r] = fmaf(a.x, w0, acc[r]);
            acc[r] = fmaf(a.y, w1, acc[r]);
            acc[r] = fmaf(a.z, w2, acc[r]);
            acc[r] = fmaf(a.w, w3, acc[r]);
        }
    }

    const float b = bias[c];
#pragma unroll
    for (int r = 0; r < ROWS; ++r) {
        float v = acc[r] + b;
        if (RELU) v = fmaxf(v, 0.0f);
        out[(size_t)(row0 + r) * NCOLS + c] = v;
    }
}

extern "C" void kernel_launch(void* const* d_in, const int* in_sizes, int n_in,
                              void* d_out, int out_size, void* d_ws, size_t ws_size,
                              hipStream_t stream) {
    const float* features = (const float*)d_in[0];
    const float* W1 = (const float*)d_in[1];
    const float* b1 = (const float*)d_in[2];
    const float* W2 = (const float*)d_in[3];
    const float* b2 = (const float*)d_in[4];
    const int* src0 = (const int*)d_in[5];
    const int* dst0 = (const int*)d_in[6];
    const int* src1 = (const int*)d_in[7];
    const int* dst1 = (const int*)d_in[8];
    const int E0 = in_sizes[5];
    const int E1 = in_sizes[7];
    const int NSRC0 = 100000, NDST0 = 20000, NDST1 = 4096;

    char* ws = (char*)d_ws;
    size_t off = 0;
    auto carve = [&](size_t bytes) -> void* {
        void* p = ws + off;
        off = (off + bytes + 255) & ~(size_t)255;
        return p;
    };
    // zero region 1: global bucket cursors (69 KB)
    int* gdc0 = (int*)carve((size_t)G0_DB * GPAD * 4);
    int* gsc0 = (int*)carve((size_t)G0_SB * GPAD * 4);
    int* gdc1 = (int*)carve((size_t)G1_DB * GPAD * 4);
    int* gsc1 = (int*)carve((size_t)G1_SB * GPAD * 4);
    const size_t zero_span1 = off;
    // dense tables (written fully by finalize; fallback zeroes them instead)
    int* od0  = (int*)carve((size_t)NSRC0 * 4);
    int* od1  = (int*)carve((size_t)NDST0 * 4);
    int* cnt0 = (int*)carve((size_t)NDST0 * 4);
    int* cnt1 = (int*)carve((size_t)NDST1 * 4);
    const size_t zero_span2 = off;   // fallback zeroes [0, zero_span2)
    uint4* pW1  = (uint4*)carve((size_t)8192 * 16);
    uint4* pW2  = (uint4*)carve((size_t)4096 * 16);
    unsigned int* bdst0 = (unsigned int*)carve((size_t)G0_DB * BCAP * 4);
    unsigned int* bsrc0 = (unsigned int*)carve((size_t)G0_SB * SCAP * 4);
    unsigned int* bdst1 = (unsigned int*)carve((size_t)G1_DB * BCAP * 4);
    unsigned int* bsrc1 = (unsigned int*)carve((size_t)G1_SB * SCAP * 4);
    int* esrc0p = (int*)carve((size_t)NDST0 * RSTRIDE * 4);
    int* esrc1p = (int*)carve((size_t)NDST1 * RSTRIDE * 4);
    unsigned short* aggb = (unsigned short*)carve((size_t)NDST0 * K_DIM * 2);
    const size_t hfeat_bytes = (size_t)NSRC0 * K_DIM * 2;
    const size_t xbufb_bytes = (size_t)NDST0 * K_DIM * 2;
    const size_t agg1b_bytes = (size_t)NDST1 * K_DIM * 2;
    const size_t need_bf16 = off + (hfeat_bytes > xbufb_bytes + agg1b_bytes
                                        ? hfeat_bytes : xbufb_bytes + agg1b_bytes);
    (void)n_in; (void)out_size;

    if (ws_size >= need_bf16) {
        unsigned short* hfeat = (unsigned short*)(ws + off);
        unsigned short* xbufb = (unsigned short*)(ws + off);   // alias: hfeat dead after gather0
        unsigned short* agg1b = (unsigned short*)(ws + off + xbufb_bytes);

        hipMemsetAsync(ws, 0, zero_span1, stream);             // 69 KB only

        const int total_f = NSRC0 * K_DIM;
        const int nA0 = (E0 + EPB - 1) / EPB;                  // 79
        const int nA1 = (E1 + EPB - 1) / EPB;                  // 16
        const int castBlocks = (total_f / 8 + 255) / 256;      // 12500
        split_mega_kernel<<<nA0 + nA1 + castBlocks + 48, 256, 0, stream>>>(
            src0, dst0, E0, src1, dst1, E1,
            gdc0, gsc0, bdst0, bsrc0, gdc1, gsc1, bdst1, bsrc1,
            nA0, nA1, features, hfeat, total_f, castBlocks,
            W1, pW1, W2, pW2);
        finalize_kernel<<<G0_DB + G1_DB + G0_SB + G1_SB, 256, 0, stream>>>(
            bdst0, gdc0, cnt0, esrc0p,
            bdst1, gdc1, cnt1, esrc1p,
            bsrc0, gsc0, od0,
            bsrc1, gsc1, od1);
        gather_bf16_kernel<true><<<(NDST0 + 3) / 4, 256, 0, stream>>>(
            hfeat, esrc0p, cnt0, od0, aggb, NDST0);
        gemm0_mfma_kernel<<<NDST0 / 16, 256, 0, stream>>>(aggb, pW1, b1, od1, xbufb, NDST0);
        gather_bf16_kernel<false><<<(NDST1 + 3) / 4, 256, 0, stream>>>(
            xbufb, esrc1p, cnt1, nullptr, agg1b, NDST1);
        gemm1_mfma_kernel<<<NDST1 / 16, 256, 0, stream>>>(agg1b, pW2, b2,
                                                          (float*)d_out, NDST1);
    } else {
        // fp32 fallback: direct atomics on dense tables
        hipMemsetAsync(ws, 0, zero_span2, stream);
        float* agg0 = (float*)carve((size_t)NDST0 * K_DIM * 4);
        float* xbuf = (float*)carve((size_t)NDST0 * K_DIM * 4);
        float* agg1 = (float*)carve((size_t)NDST1 * K_DIM * 4);
        edges_kernel<<<(E0 + E1 + 255) / 256, 256, 0, stream>>>(
            src0, dst0, od0, cnt0, esrc0p, E0,
            src1, dst1, od1, cnt1, esrc1p, E1);
        gatherf_kernel<<<(NDST0 + 3) / 4, 256, 0, stream>>>(features, esrc0p, cnt0, od0,
                                                            agg0, NDST0);
        gemm_kernel<16, 256, true><<<NDST0 / 16, 256, 0, stream>>>(agg0, W1, b1, xbuf, NDST0);
        gatherf_kernel<<<(NDST1 + 3) / 4, 256, 0, stream>>>(xbuf, esrc1p, cnt1, od1,
                                                            agg1, NDST1);
        gemm_kernel<4, 128, false><<<NDST1 / 4, 128, 0, stream>>>(agg1, W2, b2,
                                                                  (float*)d_out, NDST1);
    }
}